// Round 1
// baseline (786.939 us; speedup 1.0000x reference)
//
#include <hip/hip_runtime.h>
#include <hip/hip_bf16.h>

typedef __attribute__((ext_vector_type(8))) short short8;
typedef __attribute__((ext_vector_type(4))) float f32x4;

static __device__ __forceinline__ unsigned short f2bf(float f) {
    unsigned u = __float_as_uint(f);
    u += 0x7fffu + ((u >> 16) & 1u);
    return (unsigned short)(u >> 16);
}
static __device__ __forceinline__ float bf2f(unsigned short h) {
    return __uint_as_float(((unsigned)h) << 16);
}

// f32 -> bf16, 4 elems/thread
__global__ void cvt_kernel(const float* __restrict__ in, unsigned short* __restrict__ out, int n4) {
    int i = blockIdx.x * blockDim.x + threadIdx.x;
    if (i >= n4) return;
    float4 v = reinterpret_cast<const float4*>(in)[i];
    ushort4 o;
    o.x = f2bf(v.x); o.y = f2bf(v.y); o.z = f2bf(v.z); o.w = f2bf(v.w);
    reinterpret_cast<ushort4*>(out)[i] = o;
}

// W [K=256][N=256] f32 -> Wt [N][K] bf16
__global__ void wtr_kernel(const float* __restrict__ W, unsigned short* __restrict__ Wt) {
    int k = blockIdx.x, n = threadIdx.x;
    Wt[n * 256 + k] = f2bf(W[k * 256 + n]);
}

__global__ void count_kernel(const int* __restrict__ rows, int* __restrict__ cnt, int E) {
    int e = blockIdx.x * blockDim.x + threadIdx.x;
    if (e < E) atomicAdd(&cnt[rows[e]], 1);
}

__global__ void scan_kernel(const int* __restrict__ cnt, int* __restrict__ row_ptr,
                            int* __restrict__ cursor, int n) {
    __shared__ int sdata[1024];
    __shared__ int s_total;
    int running = 0;
    for (int base = 0; base < n; base += 1024) {
        int i = base + (int)threadIdx.x;
        int v = (i < n) ? cnt[i] : 0;
        sdata[threadIdx.x] = v;
        __syncthreads();
        for (int off = 1; off < 1024; off <<= 1) {
            int t = (threadIdx.x >= (unsigned)off) ? sdata[threadIdx.x - off] : 0;
            __syncthreads();
            sdata[threadIdx.x] += t;
            __syncthreads();
        }
        int incl = sdata[threadIdx.x];
        int excl = incl - v;
        if (i < n) { row_ptr[i] = running + excl; cursor[i] = running + excl; }
        if (threadIdx.x == 1023) s_total = incl;
        __syncthreads();
        running += s_total;
        __syncthreads();
    }
    if (threadIdx.x == 0) row_ptr[n] = running;
}

__global__ void scatter_kernel(const int* __restrict__ rows, const int* __restrict__ cols,
                               const float* __restrict__ vals, int* __restrict__ cursor,
                               int* __restrict__ ccol, float* __restrict__ cval, int E) {
    int e = blockIdx.x * blockDim.x + threadIdx.x;
    if (e < E) {
        int r = rows[e];
        int p = atomicAdd(&cursor[r], 1);
        ccol[p] = cols[e];
        cval[p] = vals[e];
    }
}

// C[M][256] = A[M][256] @ Bt[n][k]^T   (bf16 in, bf16 out, f32 accum)
// block: 256 thr = 4 waves; block tile 64 rows x 64 cols; wave: 64x16
__global__ __launch_bounds__(256) void gemm_kernel(const unsigned short* __restrict__ A,
                                                   const unsigned short* __restrict__ Bt,
                                                   unsigned short* __restrict__ C, int M) {
    const int tid = threadIdx.x;
    const int lane = tid & 63;
    const int wave = tid >> 6;
    const int m0 = blockIdx.x * 64;
    const int n0 = blockIdx.y * 64 + wave * 16;
    const int l15 = lane & 15;
    const int lk = (lane >> 4) * 8;
    f32x4 acc[4] = {};
    const unsigned short* brow = Bt + (n0 + l15) * 256 + lk;
    for (int kk = 0; kk < 256; kk += 32) {
        short8 b = *reinterpret_cast<const short8*>(brow + kk);
#pragma unroll
        for (int mf = 0; mf < 4; ++mf) {
            int row = m0 + mf * 16 + l15;
            short8 a = {};
            if (row < M) a = *reinterpret_cast<const short8*>(A + (size_t)row * 256 + kk + lk);
            acc[mf] = __builtin_amdgcn_mfma_f32_16x16x32_bf16(a, b, acc[mf], 0, 0, 0);
        }
    }
#pragma unroll
    for (int mf = 0; mf < 4; ++mf) {
#pragma unroll
        for (int r = 0; r < 4; ++r) {
            int row = m0 + mf * 16 + (lane >> 4) * 4 + r;
            if (row < M) C[(size_t)row * 256 + n0 + l15] = f2bf(acc[mf][r]);
        }
    }
}

// one wave per row; lane owns features [lane*4, lane*4+4)
template <int LAYER2>
__global__ __launch_bounds__(256) void spmm_kernel(const unsigned short* __restrict__ S,
                                                   const int* __restrict__ row_ptr,
                                                   const int* __restrict__ ccol,
                                                   const float* __restrict__ cval,
                                                   const float* __restrict__ bias,
                                                   unsigned short* __restrict__ out_bf,
                                                   float* __restrict__ out_f,
                                                   const int* __restrict__ pos_idx, int N) {
    const int lane = threadIdx.x & 63;
    const int row = blockIdx.x * 4 + (threadIdx.x >> 6);
    if (row >= N) return;
    const int s = row_ptr[row], e = row_ptr[row + 1];
    float a0 = 0.f, a1 = 0.f, a2 = 0.f, a3 = 0.f;
    for (int i = s; i < e; ++i) {
        int c = ccol[i];
        float v = cval[i];
        ushort4 u = *reinterpret_cast<const ushort4*>(S + (size_t)c * 256 + lane * 4);
        a0 += v * bf2f(u.x);
        a1 += v * bf2f(u.y);
        a2 += v * bf2f(u.z);
        a3 += v * bf2f(u.w);
    }
    const int f = lane * 4;
    a0 = fmaxf(a0 + bias[f + 0], 0.f);
    a1 = fmaxf(a1 + bias[f + 1], 0.f);
    a2 = fmaxf(a2 + bias[f + 2], 0.f);
    a3 = fmaxf(a3 + bias[f + 3], 0.f);
    if (LAYER2) {
        int orow = pos_idx[row];
        float4 o = make_float4(a0, a1, a2, a3);
        *reinterpret_cast<float4*>(out_f + (size_t)orow * 256 + f) = o;
    } else {
        ushort4 o;
        o.x = f2bf(a0); o.y = f2bf(a1); o.z = f2bf(a2); o.w = f2bf(a3);
        *reinterpret_cast<ushort4*>(out_bf + (size_t)row * 256 + f) = o;
    }
}

extern "C" void kernel_launch(void* const* d_in, const int* in_sizes, int n_in,
                              void* d_out, int out_size, void* d_ws, size_t ws_size,
                              hipStream_t stream) {
    const float* x        = (const float*)d_in[0];
    const int* adj_rows   = (const int*)d_in[1];
    const int* adj_cols   = (const int*)d_in[2];
    const float* adj_vals = (const float*)d_in[3];
    const int* pos_idx    = (const int*)d_in[5];
    const float* W1       = (const float*)d_in[6];
    const float* b1       = (const float*)d_in[7];
    const float* W2       = (const float*)d_in[8];
    const float* b2       = (const float*)d_in[9];

    const int N = in_sizes[0] / 256;
    const int E = in_sizes[1];

    char* ws = (char*)d_ws;
    size_t off = 0;
    auto alloc = [&](size_t bytes) {
        char* p = ws + off;
        off += (bytes + 255) & ~(size_t)255;
        return p;
    };
    unsigned short* xb   = (unsigned short*)alloc((size_t)N * 256 * 2); // reused as h (bf16)
    unsigned short* supb = (unsigned short*)alloc((size_t)N * 256 * 2);
    unsigned short* w1t  = (unsigned short*)alloc(256 * 256 * 2);
    unsigned short* w2t  = (unsigned short*)alloc(256 * 256 * 2);
    int* row_ptr = (int*)alloc((size_t)(N + 1) * 4);
    int* cursor  = (int*)alloc((size_t)N * 4);
    int* cnt     = (int*)alloc((size_t)N * 4);
    int* ccol    = (int*)alloc((size_t)E * 4);
    float* cval  = (float*)alloc((size_t)E * 4);
    (void)ws_size; (void)n_in;

    hipMemsetAsync(d_out, 0, (size_t)out_size * 4, stream);
    hipMemsetAsync(cnt, 0, (size_t)N * 4, stream);

    cvt_kernel<<<(N * 64 + 255) / 256, 256, 0, stream>>>(x, xb, N * 64);
    wtr_kernel<<<256, 256, 0, stream>>>(W1, w1t);
    wtr_kernel<<<256, 256, 0, stream>>>(W2, w2t);

    count_kernel<<<(E + 255) / 256, 256, 0, stream>>>(adj_rows, cnt, E);
    scan_kernel<<<1, 1024, 0, stream>>>(cnt, row_ptr, cursor, N);
    scatter_kernel<<<(E + 255) / 256, 256, 0, stream>>>(adj_rows, adj_cols, adj_vals, cursor,
                                                        ccol, cval, E);

    dim3 ggrid((N + 63) / 64, 4);
    // layer 1
    gemm_kernel<<<ggrid, 256, 0, stream>>>(xb, w1t, supb, N);
    spmm_kernel<0><<<(N + 3) / 4, 256, 0, stream>>>(supb, row_ptr, ccol, cval, b1,
                                                    xb, nullptr, nullptr, N);
    // layer 2
    gemm_kernel<<<ggrid, 256, 0, stream>>>(xb, w2t, supb, N);
    spmm_kernel<1><<<(N + 3) / 4, 256, 0, stream>>>(supb, row_ptr, ccol, cval, b2,
                                                    nullptr, (float*)d_out, pos_idx, N);
}

// Round 2
// 512.407 us; speedup vs baseline: 1.5358x; 1.5358x over previous
//
#include <hip/hip_runtime.h>
#include <hip/hip_bf16.h>

typedef __attribute__((ext_vector_type(8))) short short8;
typedef __attribute__((ext_vector_type(4))) float f32x4;

static __device__ __forceinline__ unsigned short f2bf(float f) {
    unsigned u = __float_as_uint(f);
    u += 0x7fffu + ((u >> 16) & 1u);
    return (unsigned short)(u >> 16);
}
static __device__ __forceinline__ float bf2f(unsigned short h) {
    return __uint_as_float(((unsigned)h) << 16);
}

// f32 -> bf16, 4 elems/thread
__global__ void cvt_kernel(const float* __restrict__ in, unsigned short* __restrict__ out, int n4) {
    int i = blockIdx.x * blockDim.x + threadIdx.x;
    if (i >= n4) return;
    float4 v = reinterpret_cast<const float4*>(in)[i];
    ushort4 o;
    o.x = f2bf(v.x); o.y = f2bf(v.y); o.z = f2bf(v.z); o.w = f2bf(v.w);
    reinterpret_cast<ushort4*>(out)[i] = o;
}

// W [K=256][N=256] f32 -> Wt [N][K] bf16
__global__ void wtr_kernel(const float* __restrict__ W, unsigned short* __restrict__ Wt) {
    int k = blockIdx.x, n = threadIdx.x;
    Wt[n * 256 + k] = f2bf(W[k * 256 + n]);
}

__global__ void count_kernel(const int* __restrict__ rows, int* __restrict__ cnt, int E) {
    int e = blockIdx.x * blockDim.x + threadIdx.x;
    if (e < E) atomicAdd(&cnt[rows[e]], 1);
}

// parallel scan, stage 1: per-1024-chunk exclusive scan + block sums
__global__ __launch_bounds__(1024) void scan1_kernel(const int* __restrict__ cnt,
                                                     int* __restrict__ tmp,
                                                     int* __restrict__ bsum, int n) {
    __shared__ int sdata[1024];
    int i = blockIdx.x * 1024 + threadIdx.x;
    int v = (i < n) ? cnt[i] : 0;
    sdata[threadIdx.x] = v;
    __syncthreads();
    for (int off = 1; off < 1024; off <<= 1) {
        int t = (threadIdx.x >= (unsigned)off) ? sdata[threadIdx.x - off] : 0;
        __syncthreads();
        sdata[threadIdx.x] += t;
        __syncthreads();
    }
    if (i < n) tmp[i] = sdata[threadIdx.x] - v;
    if (threadIdx.x == 1023) bsum[blockIdx.x] = sdata[1023];
}

// stage 2: single block scans the (<=64) block sums
__global__ void scan2_kernel(const int* __restrict__ bsum, int* __restrict__ boff,
                             int* __restrict__ total_out, int nb) {
    __shared__ int s[64];
    int t = threadIdx.x;
    int v = (t < nb) ? bsum[t] : 0;
    s[t] = v;
    __syncthreads();
    for (int off = 1; off < 64; off <<= 1) {
        int x = (t >= off) ? s[t - off] : 0;
        __syncthreads();
        s[t] += x;
        __syncthreads();
    }
    boff[t] = s[t] - v;
    if (t == 63) *total_out = s[63];
}

// stage 3: add block offsets, produce row_ptr and cursor
__global__ void scan3_kernel(const int* __restrict__ tmp, const int* __restrict__ boff,
                             int* __restrict__ row_ptr, int* __restrict__ cursor, int n) {
    int i = blockIdx.x * blockDim.x + threadIdx.x;
    if (i < n) {
        int v = tmp[i] + boff[i >> 10];
        row_ptr[i] = v;
        cursor[i] = v;
    }
}

__global__ void scatter_kernel(const int* __restrict__ rows, const int* __restrict__ cols,
                               const float* __restrict__ vals, int* __restrict__ cursor,
                               int2* __restrict__ cc, int E) {
    int e = blockIdx.x * blockDim.x + threadIdx.x;
    if (e < E) {
        int r = rows[e];
        int p = atomicAdd(&cursor[r], 1);
        cc[p] = make_int2(cols[e], __float_as_int(vals[e]));
    }
}

// C[M][256] = A[M][256] @ Bt[n][k]^T   (bf16 in/out, f32 accum)
// block: 4 waves; block tile 64 rows x 256 cols; wave: 64x64 via 4x4 fragments
__global__ __launch_bounds__(256) void gemm_kernel(const unsigned short* __restrict__ A,
                                                   const unsigned short* __restrict__ Bt,
                                                   unsigned short* __restrict__ C, int M) {
    const int lane = threadIdx.x & 63;
    const int wave = threadIdx.x >> 6;
    const int m0 = blockIdx.x * 64;
    const int n0 = wave * 64;
    const int l15 = lane & 15;
    const int lk = (lane >> 4) * 8;
    f32x4 acc[4][4] = {};
    const unsigned short* aptr[4];
    const unsigned short* bptr[4];
#pragma unroll
    for (int mf = 0; mf < 4; ++mf) {
        int row = m0 + mf * 16 + l15;
        aptr[mf] = A + (size_t)(row < M ? row : 0) * 256 + lk;  // clamped rows pollute only guarded C rows
    }
#pragma unroll
    for (int nf = 0; nf < 4; ++nf) bptr[nf] = Bt + (size_t)(n0 + nf * 16 + l15) * 256 + lk;
    for (int kk = 0; kk < 256; kk += 32) {
        short8 a[4], b[4];
#pragma unroll
        for (int mf = 0; mf < 4; ++mf) a[mf] = *reinterpret_cast<const short8*>(aptr[mf] + kk);
#pragma unroll
        for (int nf = 0; nf < 4; ++nf) b[nf] = *reinterpret_cast<const short8*>(bptr[nf] + kk);
#pragma unroll
        for (int mf = 0; mf < 4; ++mf)
#pragma unroll
            for (int nf = 0; nf < 4; ++nf)
                acc[mf][nf] = __builtin_amdgcn_mfma_f32_16x16x32_bf16(a[mf], b[nf], acc[mf][nf], 0, 0, 0);
    }
#pragma unroll
    for (int mf = 0; mf < 4; ++mf) {
#pragma unroll
        for (int r = 0; r < 4; ++r) {
            int row = m0 + mf * 16 + (lane >> 4) * 4 + r;
            if (row < M) {
#pragma unroll
                for (int nf = 0; nf < 4; ++nf)
                    C[(size_t)row * 256 + n0 + nf * 16 + l15] = f2bf(acc[mf][nf][r]);
            }
        }
    }
}

// one wave per row; lane owns features [lane*4, lane*4+4); edge loop unrolled x8
template <int LAYER2>
__global__ __launch_bounds__(256) void spmm_kernel(const unsigned short* __restrict__ S,
                                                   const int* __restrict__ row_ptr,
                                                   const int2* __restrict__ cc,
                                                   const float* __restrict__ bias,
                                                   unsigned short* __restrict__ out_bf,
                                                   float* __restrict__ out_f,
                                                   const int* __restrict__ pos_idx, int N) {
    const int lane = threadIdx.x & 63;
    const int row = blockIdx.x * 4 + (threadIdx.x >> 6);
    if (row >= N) return;
    const int s = row_ptr[row], e = row_ptr[row + 1];
    float a0 = 0.f, a1 = 0.f, a2 = 0.f, a3 = 0.f;
    const ushort4* Sl = reinterpret_cast<const ushort4*>(S) + lane;  // + c*64 per row
    for (int i = s; i < e; i += 8) {
        int2 p[8];
        ushort4 u[8];
        float v[8];
#pragma unroll
        for (int j = 0; j < 8; ++j) {
            int ij = i + j;
            p[j] = cc[ij < e ? ij : (e - 1)];
        }
#pragma unroll
        for (int j = 0; j < 8; ++j) u[j] = Sl[(size_t)p[j].x << 6];
#pragma unroll
        for (int j = 0; j < 8; ++j) v[j] = (i + j < e) ? __int_as_float(p[j].y) : 0.f;
#pragma unroll
        for (int j = 0; j < 8; ++j) {
            a0 += v[j] * bf2f(u[j].x);
            a1 += v[j] * bf2f(u[j].y);
            a2 += v[j] * bf2f(u[j].z);
            a3 += v[j] * bf2f(u[j].w);
        }
    }
    const int f = lane * 4;
    a0 = fmaxf(a0 + bias[f + 0], 0.f);
    a1 = fmaxf(a1 + bias[f + 1], 0.f);
    a2 = fmaxf(a2 + bias[f + 2], 0.f);
    a3 = fmaxf(a3 + bias[f + 3], 0.f);
    if (LAYER2) {
        int orow = pos_idx[row];
        float4 o = make_float4(a0, a1, a2, a3);
        *reinterpret_cast<float4*>(out_f + (size_t)orow * 256 + f) = o;
    } else {
        ushort4 o;
        o.x = f2bf(a0); o.y = f2bf(a1); o.z = f2bf(a2); o.w = f2bf(a3);
        *reinterpret_cast<ushort4*>(out_bf + (size_t)row * 256 + f) = o;
    }
}

extern "C" void kernel_launch(void* const* d_in, const int* in_sizes, int n_in,
                              void* d_out, int out_size, void* d_ws, size_t ws_size,
                              hipStream_t stream) {
    const float* x        = (const float*)d_in[0];
    const int* adj_rows   = (const int*)d_in[1];
    const int* adj_cols   = (const int*)d_in[2];
    const float* adj_vals = (const float*)d_in[3];
    const int* pos_idx    = (const int*)d_in[5];
    const float* W1       = (const float*)d_in[6];
    const float* b1       = (const float*)d_in[7];
    const float* W2       = (const float*)d_in[8];
    const float* b2       = (const float*)d_in[9];

    const int N = in_sizes[0] / 256;
    const int E = in_sizes[1];
    const int NB = (N + 1023) / 1024;

    char* ws = (char*)d_ws;
    size_t off = 0;
    auto alloc = [&](size_t bytes) {
        char* p = ws + off;
        off += (bytes + 255) & ~(size_t)255;
        return p;
    };
    unsigned short* xb   = (unsigned short*)alloc((size_t)N * 256 * 2); // reused as h (bf16)
    unsigned short* supb = (unsigned short*)alloc((size_t)N * 256 * 2);
    unsigned short* w1t  = (unsigned short*)alloc(256 * 256 * 2);
    unsigned short* w2t  = (unsigned short*)alloc(256 * 256 * 2);
    int* row_ptr = (int*)alloc((size_t)(N + 1) * 4);
    int* cursor  = (int*)alloc((size_t)N * 4);
    int* cnt     = (int*)alloc((size_t)N * 4);
    int* tmp     = (int*)alloc((size_t)N * 4);
    int* bsum    = (int*)alloc(64 * 4);
    int* boff    = (int*)alloc(64 * 4);
    int2* cc     = (int2*)alloc((size_t)E * 8);
    (void)ws_size; (void)n_in;

    hipMemsetAsync(d_out, 0, (size_t)out_size * 4, stream);
    hipMemsetAsync(cnt, 0, (size_t)N * 4, stream);

    cvt_kernel<<<(N * 64 + 255) / 256, 256, 0, stream>>>(x, xb, N * 64);
    wtr_kernel<<<256, 256, 0, stream>>>(W1, w1t);
    wtr_kernel<<<256, 256, 0, stream>>>(W2, w2t);

    count_kernel<<<(E + 255) / 256, 256, 0, stream>>>(adj_rows, cnt, E);
    scan1_kernel<<<NB, 1024, 0, stream>>>(cnt, tmp, bsum, N);
    scan2_kernel<<<1, 64, 0, stream>>>(bsum, boff, &row_ptr[N], NB);
    scan3_kernel<<<(N + 255) / 256, 256, 0, stream>>>(tmp, boff, row_ptr, cursor, N);
    scatter_kernel<<<(E + 255) / 256, 256, 0, stream>>>(adj_rows, adj_cols, adj_vals, cursor, cc, E);

    const int ggrid = (N + 63) / 64;
    // layer 1
    gemm_kernel<<<ggrid, 256, 0, stream>>>(xb, w1t, supb, N);
    spmm_kernel<0><<<(N + 3) / 4, 256, 0, stream>>>(supb, row_ptr, cc, b1, xb, nullptr, nullptr, N);
    // layer 2
    gemm_kernel<<<ggrid, 256, 0, stream>>>(xb, w2t, supb, N);
    spmm_kernel<1><<<(N + 3) / 4, 256, 0, stream>>>(supb, row_ptr, cc, b2, nullptr, (float*)d_out, pos_idx, N);
}

// Round 3
// 362.249 us; speedup vs baseline: 2.1724x; 1.4145x over previous
//
#include <hip/hip_runtime.h>
#include <hip/hip_bf16.h>

typedef __attribute__((ext_vector_type(8))) short short8;
typedef __attribute__((ext_vector_type(8))) unsigned short ushort8;
typedef __attribute__((ext_vector_type(4))) float f32x4;

#define BUK_SHIFT 7
#define BUK_ROWS 128
#define MAXBUK 400
#define NBLK_BIN 128
#define CAP 8192

static __device__ __forceinline__ unsigned short f2bf(float f) {
    unsigned u = __float_as_uint(f);
    u += 0x7fffu + ((u >> 16) & 1u);
    return (unsigned short)(u >> 16);
}
static __device__ __forceinline__ float bf2f(unsigned short h) {
    return __uint_as_float(((unsigned)h) << 16);
}

// f32 -> bf16, 4 elems/thread
__global__ void cvt_kernel(const float* __restrict__ in, unsigned short* __restrict__ out, int n4) {
    int i = blockIdx.x * blockDim.x + threadIdx.x;
    if (i >= n4) return;
    float4 v = reinterpret_cast<const float4*>(in)[i];
    ushort4 o;
    o.x = f2bf(v.x); o.y = f2bf(v.y); o.z = f2bf(v.z); o.w = f2bf(v.w);
    reinterpret_cast<ushort4*>(out)[i] = o;
}

// W [K=256][N=256] f32 -> Wt [N][K] bf16
__global__ void wtr_kernel(const float* __restrict__ W, unsigned short* __restrict__ Wt) {
    int k = blockIdx.x, n = threadIdx.x;
    Wt[n * 256 + k] = f2bf(W[k * 256 + n]);
}

// ---- CSR build: two-level LDS-binned counting sort ----

// level-1 pass A: per-block per-bucket histogram
__global__ __launch_bounds__(1024) void bin_count(const int* __restrict__ rows,
                                                  int* __restrict__ cntM, int E, int nbuk, int ce) {
    __shared__ int c[MAXBUK];
    for (int i = threadIdx.x; i < nbuk; i += 1024) c[i] = 0;
    __syncthreads();
    int s = blockIdx.x * ce, e = s + ce < E ? s + ce : E;
    for (int i = s + (int)threadIdx.x; i < e; i += 1024) atomicAdd(&c[rows[i] >> BUK_SHIFT], 1);
    __syncthreads();
    for (int i = threadIdx.x; i < nbuk; i += 1024) cntM[i * gridDim.x + blockIdx.x] = c[i];
}

// generic scan: stage 1 (per-1024 chunk)
__global__ __launch_bounds__(1024) void scan1_kernel(const int* __restrict__ in,
                                                     int* __restrict__ tmp,
                                                     int* __restrict__ bsum, int n) {
    __shared__ int sdata[1024];
    int i = blockIdx.x * 1024 + threadIdx.x;
    int v = (i < n) ? in[i] : 0;
    sdata[threadIdx.x] = v;
    __syncthreads();
    for (int off = 1; off < 1024; off <<= 1) {
        int t = (threadIdx.x >= (unsigned)off) ? sdata[threadIdx.x - off] : 0;
        __syncthreads();
        sdata[threadIdx.x] += t;
        __syncthreads();
    }
    if (i < n) tmp[i] = sdata[threadIdx.x] - v;
    if (threadIdx.x == 1023) bsum[blockIdx.x] = sdata[1023];
}

// stage 2: single block scans the (<=64) block sums
__global__ void scan2_kernel(const int* __restrict__ bsum, int* __restrict__ boff, int nb) {
    __shared__ int s[64];
    int t = threadIdx.x;
    int v = (t < nb) ? bsum[t] : 0;
    s[t] = v;
    __syncthreads();
    for (int off = 1; off < 64; off <<= 1) {
        int x = (t >= off) ? s[t - off] : 0;
        __syncthreads();
        s[t] += x;
        __syncthreads();
    }
    boff[t] = s[t] - v;
}

// stage 3: add block offsets
__global__ void scan3_kernel(const int* __restrict__ tmp, const int* __restrict__ boff,
                             int* __restrict__ out, int n) {
    int i = blockIdx.x * blockDim.x + threadIdx.x;
    if (i < n) out[i] = tmp[i] + boff[i >> 10];
}

// level-1 pass B: scatter edges into bucket-grouped order (runs are contiguous per block)
__global__ __launch_bounds__(1024) void bin_scatter(const int* __restrict__ rows,
                                                    const int* __restrict__ cols,
                                                    const float* __restrict__ vals,
                                                    const int* __restrict__ cntS,
                                                    int2* __restrict__ cc,
                                                    unsigned char* __restrict__ rb,
                                                    int E, int nbuk, int ce) {
    __shared__ int cur[MAXBUK];
    for (int i = threadIdx.x; i < nbuk; i += 1024) cur[i] = cntS[i * gridDim.x + blockIdx.x];
    __syncthreads();
    int s = blockIdx.x * ce, e = s + ce < E ? s + ce : E;
    for (int i = s + (int)threadIdx.x; i < e; i += 1024) {
        int r = rows[i];
        int p = atomicAdd(&cur[r >> BUK_SHIFT], 1);
        cc[p] = make_int2(cols[i], __float_as_int(vals[i]));
        rb[p] = (unsigned char)(r & (BUK_ROWS - 1));
    }
}

// level-2: per-bucket in-LDS sort to exact row order; emits row_ptr; in-place cc rewrite
__global__ __launch_bounds__(1024) void bucket_sort(int2* __restrict__ cc,
                                                    const unsigned char* __restrict__ rb,
                                                    const int* __restrict__ cntS,
                                                    int* __restrict__ row_ptr,
                                                    int E, int nbuk, int nblk, int N) {
    __shared__ int2 st[CAP];
    __shared__ int2 st2[CAP];
    __shared__ unsigned char rloc[CAP];
    __shared__ int cnt[BUK_ROWS];
    __shared__ int sc[BUK_ROWS];
    __shared__ int cur[BUK_ROWS];
    const int b = blockIdx.x;
    const int base = cntS[b * nblk];
    const int end = (b + 1 < nbuk) ? cntS[(b + 1) * nblk] : E;
    int sz = end - base;
    if (sz > CAP) sz = CAP;  // statistically unreachable guard
    if (threadIdx.x < BUK_ROWS) cnt[threadIdx.x] = 0;
    __syncthreads();
    for (int i = threadIdx.x; i < sz; i += 1024) {
        st[i] = cc[base + i];
        unsigned char r = rb[base + i];
        rloc[i] = r;
        atomicAdd(&cnt[r], 1);
    }
    __syncthreads();
    if (threadIdx.x < BUK_ROWS) sc[threadIdx.x] = cnt[threadIdx.x];
    __syncthreads();
    for (int off = 1; off < BUK_ROWS; off <<= 1) {
        int t = (threadIdx.x < BUK_ROWS && threadIdx.x >= (unsigned)off) ? sc[threadIdx.x - off] : 0;
        __syncthreads();
        if (threadIdx.x < BUK_ROWS) sc[threadIdx.x] += t;
        __syncthreads();
    }
    if (threadIdx.x < BUK_ROWS) {
        int excl = sc[threadIdx.x] - cnt[threadIdx.x];
        cur[threadIdx.x] = excl;
        int idx = b * BUK_ROWS + (int)threadIdx.x;
        if (idx <= N) row_ptr[idx] = base + excl;
    }
    __syncthreads();
    for (int i = threadIdx.x; i < sz; i += 1024) {
        int p = atomicAdd(&cur[rloc[i]], 1);
        st2[p] = st[i];
    }
    __syncthreads();
    for (int i = threadIdx.x; i < sz; i += 1024) cc[base + i] = st2[i];
}

// C[M][256] = A[M][256] @ Bt[n][k]^T   (bf16 in/out, f32 accum)
__global__ __launch_bounds__(256) void gemm_kernel(const unsigned short* __restrict__ A,
                                                   const unsigned short* __restrict__ Bt,
                                                   unsigned short* __restrict__ C, int M) {
    const int lane = threadIdx.x & 63;
    const int wave = threadIdx.x >> 6;
    const int m0 = blockIdx.x * 64;
    const int n0 = wave * 64;
    const int l15 = lane & 15;
    const int lk = (lane >> 4) * 8;
    f32x4 acc[4][4] = {};
    const unsigned short* aptr[4];
    const unsigned short* bptr[4];
#pragma unroll
    for (int mf = 0; mf < 4; ++mf) {
        int row = m0 + mf * 16 + l15;
        aptr[mf] = A + (size_t)(row < M ? row : 0) * 256 + lk;
    }
#pragma unroll
    for (int nf = 0; nf < 4; ++nf) bptr[nf] = Bt + (size_t)(n0 + nf * 16 + l15) * 256 + lk;
    for (int kk = 0; kk < 256; kk += 32) {
        short8 a[4], b[4];
#pragma unroll
        for (int mf = 0; mf < 4; ++mf) a[mf] = *reinterpret_cast<const short8*>(aptr[mf] + kk);
#pragma unroll
        for (int nf = 0; nf < 4; ++nf) b[nf] = *reinterpret_cast<const short8*>(bptr[nf] + kk);
#pragma unroll
        for (int mf = 0; mf < 4; ++mf)
#pragma unroll
            for (int nf = 0; nf < 4; ++nf)
                acc[mf][nf] = __builtin_amdgcn_mfma_f32_16x16x32_bf16(a[mf], b[nf], acc[mf][nf], 0, 0, 0);
    }
#pragma unroll
    for (int mf = 0; mf < 4; ++mf) {
#pragma unroll
        for (int r = 0; r < 4; ++r) {
            int row = m0 + mf * 16 + (lane >> 4) * 4 + r;
            if (row < M) {
#pragma unroll
                for (int nf = 0; nf < 4; ++nf)
                    C[(size_t)row * 256 + n0 + nf * 16 + l15] = f2bf(acc[mf][nf][r]);
            }
        }
    }
}

// SpMM: 2 rows per wave; half-wave (32 lanes) owns a row, lane owns 8 feats (16B gathers)
template <int LAYER2>
__global__ __launch_bounds__(256) void spmm_kernel(const unsigned short* __restrict__ S,
                                                   const int* __restrict__ row_ptr,
                                                   const int2* __restrict__ cc,
                                                   const float* __restrict__ bias,
                                                   unsigned short* __restrict__ out_bf,
                                                   float* __restrict__ out_f,
                                                   const int* __restrict__ pos_idx, int N) {
    const int lane = threadIdx.x & 63;
    const int wid = threadIdx.x >> 6;
    const int half = lane >> 5;
    const int l = lane & 31;
    const int row = blockIdx.x * 8 + wid * 2 + half;
    const bool valid = row < N;
    const int rowc = valid ? row : (N - 1);
    const int s = row_ptr[rowc];
    const int e = valid ? row_ptr[rowc + 1] : s;
    float a0 = 0.f, a1 = 0.f, a2 = 0.f, a3 = 0.f, a4 = 0.f, a5 = 0.f, a6 = 0.f, a7 = 0.f;
    const unsigned short* Sl = S + l * 8;
    for (int i = s; i < e; i += 8) {
        int2 p[8];
        ushort8 u[8];
        float v[8];
#pragma unroll
        for (int j = 0; j < 8; ++j) {
            int ij = i + j;
            p[j] = cc[ij < e ? ij : (e - 1)];
        }
#pragma unroll
        for (int j = 0; j < 8; ++j)
            u[j] = *reinterpret_cast<const ushort8*>(Sl + ((size_t)p[j].x << 8));
#pragma unroll
        for (int j = 0; j < 8; ++j) v[j] = (i + j < e) ? __int_as_float(p[j].y) : 0.f;
#pragma unroll
        for (int j = 0; j < 8; ++j) {
            a0 += v[j] * bf2f(u[j][0]);
            a1 += v[j] * bf2f(u[j][1]);
            a2 += v[j] * bf2f(u[j][2]);
            a3 += v[j] * bf2f(u[j][3]);
            a4 += v[j] * bf2f(u[j][4]);
            a5 += v[j] * bf2f(u[j][5]);
            a6 += v[j] * bf2f(u[j][6]);
            a7 += v[j] * bf2f(u[j][7]);
        }
    }
    if (!valid) return;
    const int f = l * 8;
    a0 = fmaxf(a0 + bias[f + 0], 0.f);
    a1 = fmaxf(a1 + bias[f + 1], 0.f);
    a2 = fmaxf(a2 + bias[f + 2], 0.f);
    a3 = fmaxf(a3 + bias[f + 3], 0.f);
    a4 = fmaxf(a4 + bias[f + 4], 0.f);
    a5 = fmaxf(a5 + bias[f + 5], 0.f);
    a6 = fmaxf(a6 + bias[f + 6], 0.f);
    a7 = fmaxf(a7 + bias[f + 7], 0.f);
    if (LAYER2) {
        int orow = pos_idx[row];
        float* o = out_f + (size_t)orow * 256 + f;
        *reinterpret_cast<float4*>(o) = make_float4(a0, a1, a2, a3);
        *reinterpret_cast<float4*>(o + 4) = make_float4(a4, a5, a6, a7);
    } else {
        ushort8 o;
        o[0] = f2bf(a0); o[1] = f2bf(a1); o[2] = f2bf(a2); o[3] = f2bf(a3);
        o[4] = f2bf(a4); o[5] = f2bf(a5); o[6] = f2bf(a6); o[7] = f2bf(a7);
        *reinterpret_cast<ushort8*>(out_bf + (size_t)row * 256 + f) = o;
    }
}

extern "C" void kernel_launch(void* const* d_in, const int* in_sizes, int n_in,
                              void* d_out, int out_size, void* d_ws, size_t ws_size,
                              hipStream_t stream) {
    const float* x        = (const float*)d_in[0];
    const int* adj_rows   = (const int*)d_in[1];
    const int* adj_cols   = (const int*)d_in[2];
    const float* adj_vals = (const float*)d_in[3];
    const int* pos_idx    = (const int*)d_in[5];
    const float* W1       = (const float*)d_in[6];
    const float* b1       = (const float*)d_in[7];
    const float* W2       = (const float*)d_in[8];
    const float* b2       = (const float*)d_in[9];

    const int N = in_sizes[0] / 256;
    const int E = in_sizes[1];
    const int nbuk = (N + BUK_ROWS - 1) >> BUK_SHIFT;       // 391
    const int n2 = nbuk * NBLK_BIN;                         // 50048
    const int nb2 = (n2 + 1023) / 1024;                     // 49
    const int ce = (E + NBLK_BIN - 1) / NBLK_BIN;           // 12500

    char* ws = (char*)d_ws;
    size_t off = 0;
    auto alloc = [&](size_t bytes) {
        char* p = ws + off;
        off += (bytes + 255) & ~(size_t)255;
        return p;
    };
    unsigned short* xb   = (unsigned short*)alloc((size_t)N * 256 * 2); // reused as h (bf16)
    unsigned short* supb = (unsigned short*)alloc((size_t)N * 256 * 2);
    unsigned short* w1t  = (unsigned short*)alloc(256 * 256 * 2);
    unsigned short* w2t  = (unsigned short*)alloc(256 * 256 * 2);
    int* row_ptr = (int*)alloc((size_t)(N + 1) * 4);
    int* cntM    = (int*)alloc((size_t)n2 * 4);
    int* cntS    = (int*)alloc((size_t)n2 * 4);
    int* tmp     = (int*)alloc((size_t)n2 * 4);
    int* bsum    = (int*)alloc(64 * 4);
    int* boff    = (int*)alloc(64 * 4);
    int2* cc     = (int2*)alloc((size_t)E * 8);
    unsigned char* rb = (unsigned char*)alloc((size_t)E);
    (void)ws_size; (void)n_in;

    hipMemsetAsync(d_out, 0, (size_t)out_size * 4, stream);

    cvt_kernel<<<(N * 64 + 255) / 256, 256, 0, stream>>>(x, xb, N * 64);
    wtr_kernel<<<256, 256, 0, stream>>>(W1, w1t);
    wtr_kernel<<<256, 256, 0, stream>>>(W2, w2t);

    // CSR build
    bin_count<<<NBLK_BIN, 1024, 0, stream>>>(adj_rows, cntM, E, nbuk, ce);
    scan1_kernel<<<nb2, 1024, 0, stream>>>(cntM, tmp, bsum, n2);
    scan2_kernel<<<1, 64, 0, stream>>>(bsum, boff, nb2);
    scan3_kernel<<<(n2 + 255) / 256, 256, 0, stream>>>(tmp, boff, cntS, n2);
    bin_scatter<<<NBLK_BIN, 1024, 0, stream>>>(adj_rows, adj_cols, adj_vals, cntS, cc, rb, E, nbuk, ce);
    bucket_sort<<<nbuk, 1024, 0, stream>>>(cc, rb, cntS, row_ptr, E, nbuk, NBLK_BIN, N);

    const int ggrid = (N + 63) / 64;
    // layer 1
    gemm_kernel<<<ggrid, 256, 0, stream>>>(xb, w1t, supb, N);
    spmm_kernel<0><<<(N + 7) / 8, 256, 0, stream>>>(supb, row_ptr, cc, b1, xb, nullptr, nullptr, N);
    // layer 2
    gemm_kernel<<<ggrid, 256, 0, stream>>>(xb, w2t, supb, N);
    spmm_kernel<1><<<(N + 7) / 8, 256, 0, stream>>>(supb, row_ptr, cc, b2, nullptr, (float*)d_out, pos_idx, N);
}